// Round 4
// baseline (9304.384 us; speedup 1.0000x reference)
//
#include <hip/hip_runtime.h>
#include <math.h>

// Problem constants
#define NTOK 131072   // 64 * 2048 tokens
#define DDIM 256      // embedding dim
#define KCB  1024     // codebook size

// Output layout (fp32, concatenated in reference return order)
static constexpr size_t O_Q = 1;                          // quantized_st
static constexpr size_t O_P = 1 + (size_t)NTOK * DDIM;    // perplexity scalar
static constexpr size_t O_E = O_P + 1;                    // encodings [NTOK, KCB]

// Scratch (inside the dead encodings region; memset after use) — float offsets
static constexpr size_t NF = (size_t)NTOK * DDIM;             // 33.55M
static constexpr size_t NE = (size_t)KCB * DDIM;              // 262144
#define CAP 32
static constexpr size_t SCRATCH_F_OFF = O_E + 2;              // f fp32            [33554436..67108868)
static constexpr size_t FB_OFF  = SCRATCH_F_OFF + NF;         // f bf16 (NF shorts)
static constexpr size_t EB_OFF  = FB_OFF + NF / 2;            // e bf16 (NE shorts)
static constexpr size_t CAND_OFF = EB_OFF + NE / 2;           // float2 [NTOK][CAP]
static constexpr size_t CNT_OFF = CAND_OFF + (size_t)NTOK * CAP * 2;  // u32 [NTOK]

// ws layout (bytes) — proven in R2
static constexpr size_t WS_IDX = 0;                        // NTOK * int
static constexpr size_t WS_EN  = (size_t)NTOK * 4;         // KCB * float (||e||^2)
static constexpr size_t WS_CNT = WS_EN + (size_t)KCB * 4;  // KCB * uint (histogram)
static constexpr size_t WS_ACC = WS_CNT + (size_t)KCB * 4; // double (loss accumulator)

#define TS 128
#define KC 32
#define LDSROW 36
#define PMARGIN 0.6f

typedef short bf16x8 __attribute__((ext_vector_type(8)));
typedef short short4v __attribute__((ext_vector_type(4)));
typedef float f32x4 __attribute__((ext_vector_type(4)));

#define MFMA16(a, b, c) __builtin_amdgcn_mfma_f32_16x16x32_bf16(a, b, c, 0, 0, 0)

static __device__ __forceinline__ short f2bf(float v) {   // RNE f32->bf16
    unsigned u = __float_as_uint(v);
    return (short)((u + 0x7fffu + ((u >> 16) & 1u)) >> 16);
}
// monotone float<->uint order-preserving encode (for LDS atomicMin over signed floats)
static __device__ __forceinline__ unsigned fenc(float d) {
    unsigned b = __float_as_uint(d);
    return (b & 0x80000000u) ? ~b : (b | 0x80000000u);
}
static __device__ __forceinline__ float fdec(unsigned k) {
    unsigned b = (k & 0x80000000u) ? (k & 0x7fffffffu) : ~k;
    return __uint_as_float(b);
}

// ---------------- K1: codebook squared norms (proven) ----------------
__global__ __launch_bounds__(64) void k_enorm(const float* __restrict__ emb,
                                              float* __restrict__ enorm) {
    int k = blockIdx.x;
    float4 v = reinterpret_cast<const float4*>(emb)[(size_t)k * 64 + threadIdx.x];
    float s = v.x * v.x + v.y * v.y + v.z * v.z + v.w * v.w;
    for (int off = 32; off >= 1; off >>= 1) s += __shfl_down(s, off, 64);
    if (threadIdx.x == 0) enorm[k] = s;
}

// ---------------- K2: emb fp32 -> bf16 ----------------
__global__ __launch_bounds__(256) void k_cvt(const float* __restrict__ src,
                                             short* __restrict__ dst, int n4) {
    int i = blockIdx.x * 256 + threadIdx.x;
    if (i >= n4) return;
    float4 v = reinterpret_cast<const float4*>(src)[i];
    short4v h; h[0] = f2bf(v.x); h[1] = f2bf(v.y); h[2] = f2bf(v.z); h[3] = f2bf(v.w);
    reinterpret_cast<short4v*>(dst)[i] = h;
}

// R2-proven fp32 inner-product micro-kernel (is-loop rolled: R1 spill post-mortem)
__device__ __forceinline__ void tile_fma(const float* __restrict__ sA,
                                         const float* __restrict__ sB,
                                         int tx, int ty, float acc[8][8]) {
#pragma unroll 1
    for (int is = 0; is < 8; ++is) {
        float4 bv[8];
#pragma unroll
        for (int c = 0; c < 8; ++c)
            bv[c] = *reinterpret_cast<const float4*>(&sB[(tx + 16 * c) * LDSROW + is * 4]);
#pragma unroll
        for (int j = 0; j < 8; ++j) {
            float4 a = *reinterpret_cast<const float4*>(&sA[(ty + 16 * j) * LDSROW + is * 4]);
#pragma unroll
            for (int c = 0; c < 8; ++c)
                acc[j][c] += a.x * bv[c].x + a.y * bv[c].y + a.z * bv[c].z + a.w * bv[c].w;
        }
    }
}

// ---------------- K3: f = x @ W^T + b (R2-proven VALU GEMM) + bf16 copy of f ----------------
__global__ __launch_bounds__(256, 2) void k_gemm1(const float* __restrict__ x,
                                                  const float* __restrict__ w,
                                                  const float* __restrict__ b,
                                                  float* __restrict__ f,
                                                  short* __restrict__ fb) {
    __shared__ float sA[TS * LDSROW];
    __shared__ float sB[TS * LDSROW];
    const int tid = threadIdx.x;
    const int tx = tid & 15, ty = tid >> 4;
    const int tb = blockIdx.x * TS;
    const int db = blockIdx.y * TS;

    float acc[8][8];
#pragma unroll
    for (int j = 0; j < 8; ++j)
#pragma unroll
        for (int c = 0; c < 8; ++c) acc[j][c] = 0.f;

    const float4* x4 = reinterpret_cast<const float4*>(x);
    const float4* w4 = reinterpret_cast<const float4*>(w);

#pragma unroll 1
    for (int kc = 0; kc < DDIM / KC; ++kc) {
        __syncthreads();
#pragma unroll
        for (int l0 = 0; l0 < 4; ++l0) {
            int l = l0 * 256 + tid;
            int row = l >> 3, i4 = l & 7;
            *reinterpret_cast<float4*>(&sA[row * LDSROW + i4 * 4]) =
                x4[(size_t)(tb + row) * 64 + kc * 8 + i4];
            *reinterpret_cast<float4*>(&sB[row * LDSROW + i4 * 4]) =
                w4[(size_t)(db + row) * 64 + kc * 8 + i4];
        }
        __syncthreads();
        tile_fma(sA, sB, tx, ty, acc);
    }

    float bias[8];
#pragma unroll
    for (int c = 0; c < 8; ++c) bias[c] = b[db + tx + 16 * c];
#pragma unroll
    for (int j = 0; j < 8; ++j) {
        size_t rowo = (size_t)(tb + ty + 16 * j) * DDIM + db;
#pragma unroll
        for (int c = 0; c < 8; ++c) {
            float v = acc[j][c] + bias[c];
            f[rowo + tx + 16 * c] = v;
            fb[rowo + tx + 16 * c] = f2bf(v);
        }
    }
}

// ---------------- K4 pass1: approximate distances via plain-bf16 MFMA + margin-append
// candidates. Only needs |d~ error| < PMARGIN for completeness; exactness lives in pass2.
__global__ __launch_bounds__(256, 3) void k_pass1(const short* __restrict__ fb,
                                                  const short* __restrict__ eb,
                                                  const float* __restrict__ enorm,
                                                  float2* __restrict__ cand,
                                                  unsigned* __restrict__ cnt) {
    __shared__ short sA[128 * 40];          // pad 8 shorts/row -> <=2-way banks
    __shared__ short sB[128 * 40];
    __shared__ unsigned s_min[128];         // fenc-encoded running min per token
    __shared__ unsigned s_cnt[128];
    __shared__ float2 s_cand[128][CAP];
    const int tid = threadIdx.x;
    const int w = tid >> 6, lane = tid & 63;
    const int wm = w & 1, wn = w >> 1;
    const int ql = lane >> 4, cl = lane & 15;
    const int tb = blockIdx.x * 128;
    const int srow = tid >> 1, shalf = tid & 1;

    if (tid < 128) { s_min[tid] = 0xFFFFFFFFu; s_cnt[tid] = 0u; }
    // (first kc-loop __syncthreads covers this init)

#pragma unroll 1
    for (int kt = 0; kt < 8; ++kt) {
        f32x4 acc[4][4];
#pragma unroll
        for (int mi = 0; mi < 4; ++mi)
#pragma unroll
            for (int ni = 0; ni < 4; ++ni)
#pragma unroll
                for (int r = 0; r < 4; ++r) acc[mi][ni][r] = 0.f;

#pragma unroll 1
        for (int kc = 0; kc < 8; ++kc) {
            __syncthreads();
            *reinterpret_cast<bf16x8*>(&sA[srow * 40 + shalf * 16]) =
                *reinterpret_cast<const bf16x8*>(&fb[(size_t)(tb + srow) * 256 + kc * 32 + shalf * 16]);
            *reinterpret_cast<bf16x8*>(&sB[srow * 40 + shalf * 16]) =
                *reinterpret_cast<const bf16x8*>(&eb[(size_t)(kt * 128 + srow) * 256 + kc * 32 + shalf * 16]);
            __syncthreads();

            bf16x8 af[4];
#pragma unroll
            for (int mi = 0; mi < 4; ++mi)
                af[mi] = *reinterpret_cast<const bf16x8*>(&sA[(wm * 64 + mi * 16 + cl) * 40 + ql * 8]);
#pragma unroll
            for (int ni = 0; ni < 4; ++ni) {
                bf16x8 bf = *reinterpret_cast<const bf16x8*>(&sB[(wn * 64 + ni * 16 + cl) * 40 + ql * 8]);
#pragma unroll
                for (int mi = 0; mi < 4; ++mi)
                    acc[mi][ni] = MFMA16(af[mi], bf, acc[mi][ni]);
            }
        }
        // epilogue: d~ = ||e||^2 - 2*dot; append if within margin of (stale-ok) running min
#pragma unroll
        for (int ni = 0; ni < 4; ++ni) {
            const int k = kt * 128 + wn * 64 + ni * 16 + cl;
            const float en = enorm[k];
#pragma unroll
            for (int mi = 0; mi < 4; ++mi)
#pragma unroll
                for (int r = 0; r < 4; ++r) {
                    float d = fmaf(-2.f, acc[mi][ni][r], en);
                    int slot = wm * 64 + mi * 16 + ql * 4 + r;   // C/D row=quad*4+reg (m89)
                    if (d < fdec(s_min[slot]) + PMARGIN) {
                        unsigned pos = atomicAdd(&s_cnt[slot], 1u);
                        if (pos < CAP) s_cand[slot][pos] = make_float2(d, __uint_as_float((unsigned)k));
                        atomicMin(&s_min[slot], fenc(d));
                    }
                }
        }
    }
    __syncthreads();
    if (tid < 128) cnt[tb + tid] = s_cnt[tid];
    for (int i = tid; i < 128 * CAP; i += 256) {
        int slot = i / CAP, j = i % CAP;   // unread slots carry garbage; pass2 reads < cnt only
        cand[(size_t)(tb + slot) * CAP + j] = s_cand[slot][j];
    }
}

// ---------------- K5 pass2: exact fp32 re-rank of candidates (np semantics, lex tie-break)
__global__ __launch_bounds__(256) void k_pass2(const float* __restrict__ f,
                                               const float* __restrict__ emb,
                                               const float* __restrict__ enorm,
                                               const float2* __restrict__ cand,
                                               const unsigned* __restrict__ cnt,
                                               int* __restrict__ idx) {
    const int t = blockIdx.x * 4 + (threadIdx.x >> 6);
    const int lane = threadIdx.x & 63;
    const float4* f4 = reinterpret_cast<const float4*>(f);
    const float4* e4 = reinterpret_cast<const float4*>(emb);
    const unsigned n = cnt[t];
    float bestd = 3.4e38f;
    int bestk = 0;
    const float4 fv = f4[(size_t)t * 64 + lane];

    if (n >= 1u && n <= (unsigned)CAP) {
        float dq = 3.4e38f; unsigned kq = 0;
        if (lane < (int)n) {
            float2 c = cand[(size_t)t * CAP + lane];
            dq = c.x; kq = __float_as_uint(c.y);
        }
        float dmin = dq;
#pragma unroll
        for (int m = 32; m >= 1; m >>= 1) dmin = fminf(dmin, __shfl_xor(dmin, m, 64));
        unsigned long long mask = __ballot(lane < (int)n && dq <= dmin + PMARGIN);
        bool first = true;
        while (mask) {
            int src = (int)__builtin_ctzll(mask); mask &= mask - 1;
            unsigned kk = __shfl(kq, src, 64);
            float4 ev = e4[(size_t)kk * 64 + lane];
            float p = fv.x * ev.x + fv.y * ev.y + fv.z * ev.z + fv.w * ev.w;
#pragma unroll
            for (int m = 32; m >= 1; m >>= 1) p += __shfl_xor(p, m, 64);
            float dex = fmaf(-2.f, p, enorm[kk]);
            if (first || dex < bestd || (dex == bestd && (int)kk < bestk)) {
                bestd = dex; bestk = (int)kk; first = false;
            }
        }
    } else {
        // overflow (or impossible n==0) fallback: exact scan over all K — always correct
        for (int kk = 0; kk < KCB; ++kk) {
            float4 ev = e4[(size_t)kk * 64 + lane];
            float p = fv.x * ev.x + fv.y * ev.y + fv.z * ev.z + fv.w * ev.w;
#pragma unroll
            for (int m = 32; m >= 1; m >>= 1) p += __shfl_xor(p, m, 64);
            float dex = fmaf(-2.f, p, enorm[kk]);
            if (dex < bestd) { bestd = dex; bestk = kk; }  // ascending kk => lex ok
        }
    }
    if (lane == 0) idx[t] = bestk;
}

// ---------------- K6: quantized gather + loss partial + histogram (proven) ----------------
__global__ __launch_bounds__(256) void k_epilogue(const float* __restrict__ x,
                                                  const float* __restrict__ emb,
                                                  const int* __restrict__ idx,
                                                  float* __restrict__ out,
                                                  unsigned* __restrict__ counts,
                                                  double* __restrict__ lossacc) {
    const int tid = threadIdx.x;
    const int tb = blockIdx.x * 64;
    const float4* x4 = reinterpret_cast<const float4*>(x);
    const float4* e4 = reinterpret_cast<const float4*>(emb);
    float local = 0.f;
#pragma unroll
    for (int it = 0; it < 16; ++it) {
        int l = it * 256 + tid;
        int tok = l >> 6, q = l & 63;
        int t = tb + tok;
        int id = idx[t];
        if (q == 0) atomicAdd(&counts[id], 1u);
        float4 xv = x4[(size_t)t * 64 + q];
        float4 ev = e4[(size_t)id * 64 + q];
        size_t o = O_Q + (size_t)t * DDIM + (size_t)q * 4;
        out[o] = ev.x; out[o + 1] = ev.y; out[o + 2] = ev.z; out[o + 3] = ev.w;
        float dx = ev.x - xv.x, dy = ev.y - xv.y, dz = ev.z - xv.z, dw = ev.w - xv.w;
        local += dx * dx + dy * dy + dz * dz + dw * dw;
    }
    for (int off = 32; off >= 1; off >>= 1) local += __shfl_down(local, off, 64);
    __shared__ float wsum[4];
    if ((tid & 63) == 0) wsum[tid >> 6] = local;
    __syncthreads();
    if (tid == 0)
        atomicAdd(lossacc, (double)(wsum[0] + wsum[1] + wsum[2] + wsum[3]));
}

// ---------------- K7: scatter one-hot (proven) ----------------
__global__ __launch_bounds__(256) void k_scatter(const int* __restrict__ idx,
                                                 float* __restrict__ out) {
    int t = blockIdx.x * 256 + threadIdx.x;
    out[O_E + (size_t)t * KCB + idx[t]] = 1.0f;
}

// ---------------- K8: loss + perplexity finalize (proven) ----------------
__global__ __launch_bounds__(1024) void k_final(const unsigned* __restrict__ counts,
                                                const double* __restrict__ lossacc,
                                                float* __restrict__ out) {
    int tid = threadIdx.x;
    double p = (double)counts[tid] / (double)NTOK;
    double term = p * log(p + 1e-10);
    for (int off = 32; off >= 1; off >>= 1) term += __shfl_down(term, off, 64);
    __shared__ double sw[16];
    if ((tid & 63) == 0) sw[tid >> 6] = term;
    __syncthreads();
    if (tid == 0) {
        double s = 0.0;
        for (int i = 0; i < 16; ++i) s += sw[i];
        out[O_P] = (float)exp(-s);
        out[0]   = (float)(0.25 * lossacc[0] / ((double)NTOK * (double)DDIM));
    }
}

extern "C" void kernel_launch(void* const* d_in, const int* in_sizes, int n_in,
                              void* d_out, int out_size, void* d_ws, size_t ws_size,
                              hipStream_t stream) {
    const float* x   = (const float*)d_in[0];  // [64,2048,256]
    const float* w   = (const float*)d_in[1];  // [256,256]
    const float* b   = (const float*)d_in[2];  // [256]
    const float* emb = (const float*)d_in[3];  // [1024,256]
    float* out = (float*)d_out;

    int*      idx    = (int*)((char*)d_ws + WS_IDX);
    float*    enorm  = (float*)((char*)d_ws + WS_EN);
    unsigned* counts = (unsigned*)((char*)d_ws + WS_CNT);
    double*   acc    = (double*)((char*)d_ws + WS_ACC);

    float*    f    = out + SCRATCH_F_OFF;
    short*    fb   = (short*)(out + FB_OFF);
    short*    eb   = (short*)(out + EB_OFF);
    float2*   cand = (float2*)(out + CAND_OFF);
    unsigned* cnt  = (unsigned*)(out + CNT_OFF);

    hipMemsetAsync((char*)d_ws + WS_CNT, 0, (size_t)KCB * 4 + 8, stream);

    k_enorm<<<KCB, 64, 0, stream>>>(emb, enorm);
    k_cvt  <<<(int)(NE / 4 / 256), 256, 0, stream>>>(emb, eb, (int)(NE / 4));

    k_gemm1<<<dim3(NTOK / TS, DDIM / TS), 256, 0, stream>>>(x, w, b, f, fb);
    k_pass1<<<NTOK / 128, 256, 0, stream>>>(fb, eb, enorm, cand, cnt);
    k_pass2<<<NTOK / 4,   256, 0, stream>>>(f, emb, enorm, cand, cnt, idx);

    k_epilogue<<<NTOK / 64, 256, 0, stream>>>(x, emb, idx, out, counts, acc);

    hipMemsetAsync(out + O_E, 0, (size_t)NTOK * KCB * 4, stream);
    k_scatter<<<NTOK / 256, 256, 0, stream>>>(idx, out);
    k_final  <<<1, 1024, 0, stream>>>(counts, acc, out);
}